// Round 8
// baseline (1177.724 us; speedup 1.0000x reference)
//
#include <hip/hip_runtime.h>
#include <hip/hip_bf16.h>
#include <float.h>

// Problem constants
#define Bn   16
#define Nn   32768
#define Cn   64
#define Sn   1024
#define Kn   32
#define On   1024
#define KCn  2048            // K*C
#define TGT  48              // candidate rank target for fp64 rerank
#define MAXC 384             // candidate list capacity per row
#define BK   64              // GEMM K-step (2 x k32 sub-tiles per barrier pair)
#define LDB  40              // LDS sub-row stride (u16); 80B keeps uint4 aligned
#define SUB  (128*LDB)       // one k32 sub-buffer (u16 elems)
#define FEATS_ELEMS (Bn*On*Cn)          // 1,048,576
#define SAMP_ELEMS  (Bn*Sn*Cn)          // 1,048,576

typedef unsigned short u16;
typedef unsigned int   u32;
typedef short v8s __attribute__((ext_vector_type(8)));
typedef float v4f __attribute__((ext_vector_type(4)));

// ws layout (bytes).  d2 (KNN, 134.2MB @0) is temporally disjoint from
// HT+xb which reuse the same region after select consumes d2.
#define HT_OFF   0ull                    // bf16 [16][2048][1024] = 67,108,864
#define XB_OFF   67108864ull             // bf16 [16][32768][64]  = 67,108,864
#define D2_OFF   0ull                    // fp32 [1024][32768]    = 134,217,728 (KNN phase only)
#define P2_OFF   134217728ull            // 131,072
#define NBR_OFF  134348800ull            // 131,072
#define W1H_OFF  134676480ull            // 2,097,152 each
#define W1L_OFF  136773632ull
#define W2H_OFF  138870784ull
#define W2L_OFF  140967936ull
#define CAND_OFF 143065088ull            // 1024*384*4 = 1,572,864
#define CNT_OFF  144637952ull            // 1024*4
// total ws requirement: ~144.7 MB (prev verified runs used up to 151.5 MB)

__device__ __forceinline__ u16 rne16(float f) {       // fp32 -> bf16 RNE
  u32 u = __float_as_uint(f);
  return (u16)((u + 0x7FFFu + ((u >> 16) & 1u)) >> 16);
}
__device__ __forceinline__ v4f vmax4(v4f a, v4f b) {
  v4f r; r[0]=fmaxf(a[0],b[0]); r[1]=fmaxf(a[1],b[1]);
  r[2]=fmaxf(a[2],b[2]); r[3]=fmaxf(a[3],b[3]); return r;
}
union V16 { uint4 v; u32 u[4]; u16 s[8]; };
union US4 { ushort4 v; u16 s[4]; };

// ---------------------------------------------------------------- p2 = |x0_n|^2
__global__ __launch_bounds__(256) void p2_kernel(const float* __restrict__ x,
                                                 float* __restrict__ p2) {
  int n = blockIdx.x * 256 + threadIdx.x;
  const float* r = x + (size_t)n * Cn;
  float s = 0.f;
  #pragma unroll
  for (int c = 0; c < Cn; ++c) s += r[c] * r[c];
  p2[n] = s;
}

// ------------------------------------------------- d2[s][n] = q2 + p2 - 2*dot
__global__ __launch_bounds__(256) void dist_kernel(const float* __restrict__ x,
                                                   const int* __restrict__ sidx,
                                                   const float* __restrict__ p2,
                                                   float* __restrict__ d2) {
  const int n0 = blockIdx.x * 128;
  const int s0 = blockIdx.y * 128;
  __shared__ float Qs[64][129];
  __shared__ float Ps[64][129];
  __shared__ float sq2[128], sp2[128];
  __shared__ int   sIdx[128];
  const int t = threadIdx.x;
  const int tx = t & 15, ty = t >> 4;

  if (t < 128) { int ss = sidx[s0 + t]; sIdx[t] = ss; sq2[t] = p2[ss]; }
  else         { sp2[t - 128] = p2[n0 + t - 128]; }
  __syncthreads();

  #pragma unroll
  for (int r = 0; r < 32; ++r) {
    int id = r * 256 + t;
    int c_l = id & 63, r_l = id >> 6;
    Qs[c_l][r_l] = x[(size_t)sIdx[r_l] * Cn + c_l];
    Ps[c_l][r_l] = x[(size_t)(n0 + r_l) * Cn + c_l];
  }
  __syncthreads();

  float acc[8][8];
  #pragma unroll
  for (int i = 0; i < 8; ++i)
    #pragma unroll
    for (int j = 0; j < 8; ++j) acc[i][j] = 0.f;

  #pragma unroll 4
  for (int c = 0; c < 64; ++c) {
    float a[8], b[8];
    #pragma unroll
    for (int i = 0; i < 8; ++i) a[i] = Qs[c][ty * 8 + i];
    #pragma unroll
    for (int j = 0; j < 8; ++j) b[j] = Ps[c][tx * 8 + j];
    #pragma unroll
    for (int i = 0; i < 8; ++i)
      #pragma unroll
      for (int j = 0; j < 8; ++j) acc[i][j] += a[i] * b[j];
  }

  #pragma unroll
  for (int i = 0; i < 8; ++i) {
    int srow = s0 + ty * 8 + i;
    float q2v = sq2[ty * 8 + i];
    float out[8];
    #pragma unroll
    for (int j = 0; j < 8; ++j) out[j] = q2v + sp2[tx * 8 + j] - 2.f * acc[i][j];
    float4* dst = (float4*)&d2[(size_t)srow * Nn + n0 + tx * 8];
    dst[0] = make_float4(out[0], out[1], out[2], out[3]);
    dst[1] = make_float4(out[4], out[5], out[6], out[7]);
  }
}

// ---------------- candidate select: two-level histogram radix-select.
__device__ __forceinline__ u32 f2key(float d) {
  u32 b = __float_as_uint(d);
  return (b & 0x80000000u) ? ~b : (b | 0x80000000u);
}

__global__ __launch_bounds__(256) void select_kernel(const float* __restrict__ d2,
                                                     int* __restrict__ cand,
                                                     int* __restrict__ candcnt) {
  const int s = blockIdx.x;
  const float* row = d2 + (size_t)s * Nn;
  const int t = threadIdx.x;
  __shared__ u32 hist[2048];
  __shared__ u32 partial[256];
  __shared__ u32 bc[4];           // [0]=b1, [1]=cum-before-b1, [2]=thr22, [3]=count

  // ---- pass A: level-1 histogram (key bits [31:21])
  #pragma unroll
  for (int i = 0; i < 8; ++i) hist[t * 8 + i] = 0;
  __syncthreads();
  for (int i = t; i < Nn; i += 256)
    atomicAdd(&hist[f2key(row[i]) >> 21], 1u);
  __syncthreads();

  u32 lsum = 0;
  #pragma unroll
  for (int i = 0; i < 8; ++i) lsum += hist[t * 8 + i];
  partial[t] = lsum;
  __syncthreads();
  for (int off = 1; off < 256; off <<= 1) {
    u32 add = (t >= off) ? partial[t - off] : 0;
    __syncthreads();
    partial[t] += add;
    __syncthreads();
  }
  {
    u32 c = (t == 0) ? 0 : partial[t - 1];
    #pragma unroll
    for (int i = 0; i < 8; ++i) {
      u32 h = hist[t * 8 + i];
      if (c < TGT && c + h >= TGT) { bc[0] = t * 8 + i; bc[1] = c; }
      c += h;
    }
  }
  __syncthreads();
  const u32 b1 = bc[0], cumb = bc[1];
  const u32 rem = TGT - cumb;                 // in [1, TGT]

  // ---- pass B: level-2 histogram within bin b1 (key bits [20:10])
  __syncthreads();
  #pragma unroll
  for (int i = 0; i < 8; ++i) hist[t * 8 + i] = 0;
  __syncthreads();
  for (int i = t; i < Nn; i += 256) {
    u32 key = f2key(row[i]);
    if ((key >> 21) == b1) atomicAdd(&hist[(key >> 10) & 0x7FFu], 1u);
  }
  __syncthreads();

  lsum = 0;
  #pragma unroll
  for (int i = 0; i < 8; ++i) lsum += hist[t * 8 + i];
  partial[t] = lsum;
  __syncthreads();
  for (int off = 1; off < 256; off <<= 1) {
    u32 add = (t >= off) ? partial[t - off] : 0;
    __syncthreads();
    partial[t] += add;
    __syncthreads();
  }
  {
    u32 c = (t == 0) ? 0 : partial[t - 1];
    #pragma unroll
    for (int i = 0; i < 8; ++i) {
      u32 h = hist[t * 8 + i];
      if (c < rem && c + h >= rem) bc[2] = (b1 << 11) | (t * 8 + i);
      c += h;
    }
  }
  if (t == 0) bc[3] = 0;
  __syncthreads();
  const u32 thr22 = bc[2];

  // ---- pass C: compact candidates (22-bit prefix <= thr22)
  for (int i = t; i < Nn; i += 256) {
    u32 key = f2key(row[i]);
    if ((key >> 10) <= thr22) {
      u32 pos = atomicAdd(&bc[3], 1u);
      if (pos < MAXC) cand[s * MAXC + pos] = i;
    }
  }
  __syncthreads();
  if (t == 0) candcnt[s] = (int)(bc[3] < MAXC ? bc[3] : MAXC);
}

// ---------------------- fp64 rerank: exact top-32 of the candidate list.
__global__ __launch_bounds__(64) void rerank_kernel(const float* __restrict__ x,
                                                    const int* __restrict__ sidx,
                                                    const int* __restrict__ cand,
                                                    const int* __restrict__ candcnt,
                                                    int* __restrict__ nbr) {
  const int s = blockIdx.x;
  const int lane = threadIdx.x;
  __shared__ double q[64];
  q[lane] = (double)x[(size_t)sidx[s] * Cn + lane];
  __syncthreads();

  const int cnt = candcnt[s];
  const int niter = (cnt + 63) >> 6;          // <= 6
  unsigned long long keys[MAXC / 64];
  #pragma unroll
  for (int it = 0; it < MAXC / 64; ++it) keys[it] = ~0ull;

  for (int it = 0; it < niter; ++it) {
    int idx = it * 64 + lane;
    if (idx < cnt) {
      int ci = cand[s * MAXC + idx];
      const float* p = x + (size_t)ci * Cn;
      double acc = 0.0;
      #pragma unroll
      for (int c = 0; c < 64; ++c) {
        double d = q[c] - (double)p[c];
        acc = fma(d, d, acc);
      }
      unsigned long long bits = __double_as_longlong(acc);
      keys[it] = (bits & ~0x7FFFull) | (unsigned long long)(u32)ci;
    }
  }

  for (int r = 0; r < Kn; ++r) {
    unsigned long long m = keys[0];
    #pragma unroll
    for (int it = 1; it < MAXC / 64; ++it) m = keys[it] < m ? keys[it] : m;
    #pragma unroll
    for (int w = 32; w > 0; w >>= 1) {
      unsigned long long o = __shfl_xor(m, w, 64);
      m = o < m ? o : m;
    }
    #pragma unroll
    for (int it = 0; it < MAXC / 64; ++it)
      if (keys[it] == m) keys[it] = ~0ull;    // keys unique (distinct idx)
    if (lane == 0) nbr[s * Kn + r] = (int)(m & 0x7FFFull);
  }
}

// --------------------------------------------------- sampled_x gather (output)
__global__ __launch_bounds__(256) void sample_kernel(const float* __restrict__ x,
                                                     const int* __restrict__ sidx,
                                                     float* __restrict__ out2) {
  int i = blockIdx.x * 256 + threadIdx.x;
  int c = i & 63;
  int s = (i >> 6) & (Sn - 1);
  int b = i >> 16;
  out2[i] = x[(size_t)b * Nn * Cn + (size_t)sidx[s] * Cn + c];
}

// ------------------------------------------------ x fp32 -> bf16 (RNE), 8/thread
__global__ __launch_bounds__(256) void cvt_x_kernel(const float* __restrict__ x,
                                                    u16* __restrict__ xb) {
  size_t i = ((size_t)blockIdx.x * 256 + threadIdx.x) * 8;
  float4 f0 = *(const float4*)(x + i);
  float4 f1 = *(const float4*)(x + i + 4);
  uint4 o;
  o.x = (u32)rne16(f0.x) | ((u32)rne16(f0.y) << 16);
  o.y = (u32)rne16(f0.z) | ((u32)rne16(f0.w) << 16);
  o.z = (u32)rne16(f1.x) | ((u32)rne16(f1.y) << 16);
  o.w = (u32)rne16(f1.z) | ((u32)rne16(f1.w) << 16);
  *(uint4*)(xb + i) = o;
}

// --------------------------- W fp32 -> bf16 hi + bf16 lo (split), 4/thread
__global__ __launch_bounds__(256) void cvt_split_kernel(const float* __restrict__ src,
                                                        u16* __restrict__ dh,
                                                        u16* __restrict__ dl) {
  size_t i = ((size_t)blockIdx.x * 256 + threadIdx.x) * 4;
  float4 f = *(const float4*)(src + i);
  float fv[4] = {f.x, f.y, f.z, f.w};
  US4 oh, ol;
  #pragma unroll
  for (int j = 0; j < 4; ++j) {
    u16 h = rne16(fv[j]);
    float hf = __uint_as_float((u32)h << 16);
    oh.s[j] = h;
    ol.s[j] = rne16(fv[j] - hf);
  }
  *(ushort4*)(dh + i) = oh.v;
  *(ushort4*)(dl + i) = ol.v;
}

// ---------------- GEMM1 (MFMA): HT[b][kc][o] = relu(b1[o] + sum_s W1[o,s]*G[s,kc])
// BK=64 (2 x k32 sub-buffers), register-prefetch software pipeline:
// loads for step i+1 are issued BEFORE the MFMA cluster of step i, so the
// ~500cy gather latency hides under 64 MFMAs instead of stalling the
// barrier pair. 16 barrier pairs (was 32).
__global__ __launch_bounds__(256) void gemm1_mfma(const u16* __restrict__ xb,
                                                  const u16* __restrict__ W1h,
                                                  const u16* __restrict__ W1l,
                                                  const float* __restrict__ b1,
                                                  const int* __restrict__ nbr,
                                                  u16* __restrict__ HT) {
  const int b = blockIdx.z, o0 = blockIdx.y * 128, kc0 = blockIdx.x * 128;
  __shared__ u16 Ah[2 * SUB];       // [ks][row][LDB]
  __shared__ u16 Al[2 * SUB];
  __shared__ u16 Bs[2 * SUB];       // [ks][n][LDB] (transposed during staging)
  __shared__ float b1s[128];
  const int t = threadIdx.x, lane = t & 63, w = t >> 6;
  const int wr = w >> 1, wc = w & 1;
  if (t < 128) b1s[t] = b1[o0 + t];

  v4f acc[4][4];
  #pragma unroll
  for (int i = 0; i < 4; ++i)
    #pragma unroll
    for (int j = 0; j < 4; ++j) { v4f z = {0.f,0.f,0.f,0.f}; acc[i][j] = z; }

  // A staging: thread -> row t>>1, k-half (t&1)*32 (= sub-buffer t&1)
  const int arow = t >> 1, ahalf = t & 1;
  const u16* aH = W1h + (size_t)(o0 + arow) * Sn + ahalf * 32;
  const u16* aL = W1l + (size_t)(o0 + arow) * Sn + ahalf * 32;
  u16* AhDst = &Ah[ahalf * SUB + arow * LDB];
  u16* AlDst = &Al[ahalf * SUB + arow * LDB];
  // B staging: thread -> 4 consecutive s (4 nbr rows), 8 n-cols
  const int s4 = (t & 15) * 4, n0 = (t >> 4) * 8;
  const int bks = s4 >> 5, bk = s4 & 31;
  const int kknn = (kc0 + n0) >> 6;           // knn slot (same for the 8 n)
  const int cc = (kc0 + n0) & 63;             // c offset (mult of 8)
  const u16* xbb = xb + (size_t)b * Nn * Cn;

  uint4 pAh[4], pAl[4], pB[4];
  #define G1_LOAD(S0)                                                        \
    { _Pragma("unroll")                                                      \
      for (int j = 0; j < 4; ++j) {                                          \
        pAh[j] = *(const uint4*)(aH + (S0) + j * 8);                         \
        pAl[j] = *(const uint4*)(aL + (S0) + j * 8);                         \
      }                                                                      \
      _Pragma("unroll")                                                      \
      for (int m = 0; m < 4; ++m) {                                          \
        int rr = nbr[((S0) + s4 + m) * Kn + kknn];                           \
        pB[m] = *(const uint4*)(xbb + (size_t)rr * Cn + cc);                 \
      } }

  G1_LOAD(0);
  for (int s0 = 0; s0 < Sn; s0 += BK) {
    __syncthreads();                          // prior step's frag reads done
    #pragma unroll
    for (int j = 0; j < 4; ++j) {
      *(uint4*)(AhDst + j * 8) = pAh[j];
      *(uint4*)(AlDst + j * 8) = pAl[j];
    }
    { V16 q0, q1, q2, q3;
      q0.v = pB[0]; q1.v = pB[1]; q2.v = pB[2]; q3.v = pB[3];
      #pragma unroll
      for (int i = 0; i < 8; ++i) {           // transpose: 4 s per n-row
        US4 wv; wv.s[0] = q0.s[i]; wv.s[1] = q1.s[i];
        wv.s[2] = q2.s[i]; wv.s[3] = q3.s[i];
        *(ushort4*)&Bs[bks * SUB + (n0 + i) * LDB + bk] = wv.v;
      } }
    __syncthreads();                          // tile ready
    if (s0 + BK < Sn) G1_LOAD(s0 + BK);       // prefetch next (hides latency)

    const int lm = lane & 15, ko = (lane >> 4) * 8;
    #pragma unroll
    for (int ks = 0; ks < 2; ++ks) {
      v8s afh[4], afl[4], bf[4];
      #pragma unroll
      for (int i = 0; i < 4; ++i) {
        afh[i] = *(v8s*)&Ah[ks * SUB + (wr * 64 + i * 16 + lm) * LDB + ko];
        afl[i] = *(v8s*)&Al[ks * SUB + (wr * 64 + i * 16 + lm) * LDB + ko];
        bf[i]  = *(v8s*)&Bs[ks * SUB + (wc * 64 + i * 16 + lm) * LDB + ko];
      }
      #pragma unroll
      for (int mi = 0; mi < 4; ++mi)
        #pragma unroll
        for (int nj = 0; nj < 4; ++nj) {
          acc[mi][nj] = __builtin_amdgcn_mfma_f32_16x16x32_bf16(afh[mi], bf[nj], acc[mi][nj], 0, 0, 0);
          acc[mi][nj] = __builtin_amdgcn_mfma_f32_16x16x32_bf16(afl[mi], bf[nj], acc[mi][nj], 0, 0, 0);
        }
    }
  }
  #undef G1_LOAD

  const size_t HTb = (size_t)b * KCn * On;
  const int lm = lane & 15;
  const int orow = wr * 64 + (lane >> 4) * 4;
  #pragma unroll
  for (int mi = 0; mi < 4; ++mi) {
    #pragma unroll
    for (int nj = 0; nj < 4; ++nj) {
      int kc = kc0 + wc * 64 + nj * 16 + lm;
      int om = orow + mi * 16;
      US4 outp;
      #pragma unroll
      for (int r = 0; r < 4; ++r) {
        float v = acc[mi][nj][r] + b1s[om + r];
        v = v > 0.f ? v : 0.f;
        outp.s[r] = rne16(v);
      }
      *(ushort4*)&HT[HTb + (size_t)kc * On + o0 + om] = outp.v;
    }
  }
}

// ------- GEMM2 (MFMA) + in-register max over k, writes feats directly.
// Same BK=64 + register-prefetch pipeline. B rows are o-contiguous in HT
// (no transpose needed).
__global__ __launch_bounds__(256) void gemm2_mfma(const u16* __restrict__ HT,
                                                  const u16* __restrict__ W2h,
                                                  const u16* __restrict__ W2l,
                                                  const float* __restrict__ b2,
                                                  float* __restrict__ feats) {
  const int b = blockIdx.z, p0 = blockIdx.y * 128, c0 = blockIdx.x * 4;
  __shared__ u16 Ah[2 * SUB];
  __shared__ u16 Al[2 * SUB];
  __shared__ u16 Bs[2 * SUB];
  __shared__ float b2s[128];
  const int t = threadIdx.x, lane = t & 63, w = t >> 6;
  const int wr = w >> 1, wc = w & 1;
  if (t < 128) b2s[t] = b2[p0 + t];

  v4f acc[4][4];
  #pragma unroll
  for (int i = 0; i < 4; ++i)
    #pragma unroll
    for (int j = 0; j < 4; ++j) { v4f z = {0.f,0.f,0.f,0.f}; acc[i][j] = z; }

  const int arow = t >> 1, ahalf = t & 1;
  const u16* aH = W2h + (size_t)(p0 + arow) * On + ahalf * 32;
  const u16* aL = W2l + (size_t)(p0 + arow) * On + ahalf * 32;
  u16* AhDst = &Ah[ahalf * SUB + arow * LDB];
  u16* AlDst = &Al[ahalf * SUB + arow * LDB];
  // B: row n = t>>1 (k = n&31, cq = n>>5), o-half = t&1
  const int kcn = (arow & 31) * 64 + c0 + (arow >> 5);
  const u16* bSrc = HT + (size_t)b * KCn * On + (size_t)kcn * On + ahalf * 32;
  u16* BDst = &Bs[ahalf * SUB + arow * LDB];

  uint4 pAh[4], pAl[4], pB[4];
  #define G2_LOAD(O0)                                                        \
    { _Pragma("unroll")                                                      \
      for (int j = 0; j < 4; ++j) {                                          \
        pAh[j] = *(const uint4*)(aH + (O0) + j * 8);                         \
        pAl[j] = *(const uint4*)(aL + (O0) + j * 8);                         \
        pB[j]  = *(const uint4*)(bSrc + (O0) + j * 8);                       \
      } }

  G2_LOAD(0);
  for (int o0k = 0; o0k < On; o0k += BK) {
    __syncthreads();
    #pragma unroll
    for (int j = 0; j < 4; ++j) {
      *(uint4*)(AhDst + j * 8) = pAh[j];
      *(uint4*)(AlDst + j * 8) = pAl[j];
      *(uint4*)(BDst  + j * 8) = pB[j];
    }
    __syncthreads();
    if (o0k + BK < On) G2_LOAD(o0k + BK);

    const int lm = lane & 15, ko = (lane >> 4) * 8;
    #pragma unroll
    for (int ks = 0; ks < 2; ++ks) {
      v8s afh[4], afl[4], bf[4];
      #pragma unroll
      for (int i = 0; i < 4; ++i) {
        afh[i] = *(v8s*)&Ah[ks * SUB + (wr * 64 + i * 16 + lm) * LDB + ko];
        afl[i] = *(v8s*)&Al[ks * SUB + (wr * 64 + i * 16 + lm) * LDB + ko];
        bf[i]  = *(v8s*)&Bs[ks * SUB + (wc * 64 + i * 16 + lm) * LDB + ko];
      }
      #pragma unroll
      for (int mi = 0; mi < 4; ++mi)
        #pragma unroll
        for (int nj = 0; nj < 4; ++nj) {
          acc[mi][nj] = __builtin_amdgcn_mfma_f32_16x16x32_bf16(afh[mi], bf[nj], acc[mi][nj], 0, 0, 0);
          acc[mi][nj] = __builtin_amdgcn_mfma_f32_16x16x32_bf16(afl[mi], bf[nj], acc[mi][nj], 0, 0, 0);
        }
    }
  }
  #undef G2_LOAD

  const int lm = lane & 15;
  const int prow = wr * 64 + (lane >> 4) * 4;
  #pragma unroll
  for (int mi = 0; mi < 4; ++mi) {
    v4f m0 = vmax4(acc[mi][0], acc[mi][1]);   // cq = wc*2
    v4f m1 = vmax4(acc[mi][2], acc[mi][3]);   // cq = wc*2 + 1
    float v0[4], v1[4];
    #pragma unroll
    for (int r = 0; r < 4; ++r) {
      float a0 = m0[r], a1 = m1[r];
      #pragma unroll
      for (int msk = 1; msk < 16; msk <<= 1) {
        a0 = fmaxf(a0, __shfl_xor(a0, msk, 64));
        a1 = fmaxf(a1, __shfl_xor(a1, msk, 64));
      }
      v0[r] = a0; v1[r] = a1;
    }
    if (lm == 0) {
      #pragma unroll
      for (int r = 0; r < 4; ++r) {
        int p = prow + mi * 16 + r;
        float bias = b2s[p];
        size_t base = ((size_t)b * On + p0 + p) * Cn + c0 + wc * 2;
        feats[base]     = v0[r] + bias;
        feats[base + 1] = v1[r] + bias;
      }
    }
  }
}

extern "C" void kernel_launch(void* const* d_in, const int* in_sizes, int n_in,
                              void* d_out, int out_size, void* d_ws, size_t ws_size,
                              hipStream_t stream) {
  const float* x    = (const float*)d_in[0];
  const int*   sidx = (const int*)d_in[1];
  const float* W1   = (const float*)d_in[2];
  const float* b1   = (const float*)d_in[3];
  const float* W2   = (const float*)d_in[4];
  const float* b2   = (const float*)d_in[5];
  float* feats = (float*)d_out;                       // [B][OUT][C]
  float* out2  = (float*)d_out + FEATS_ELEMS;         // [B][S][C]

  char* ws = (char*)d_ws;
  float* d2   = (float*)(ws + D2_OFF);
  float* p2   = (float*)(ws + P2_OFF);
  int*   nbr  = (int*)  (ws + NBR_OFF);
  int*   cand = (int*)  (ws + CAND_OFF);
  int*   ccnt = (int*)  (ws + CNT_OFF);
  u16*   HT   = (u16*)  (ws + HT_OFF);
  u16*   xb   = (u16*)  (ws + XB_OFF);
  u16*   W1h  = (u16*)  (ws + W1H_OFF);
  u16*   W1l  = (u16*)  (ws + W1L_OFF);
  u16*   W2h  = (u16*)  (ws + W2H_OFF);
  u16*   W2l  = (u16*)  (ws + W2L_OFF);

  // KNN phase
  p2_kernel<<<dim3(Nn / 256), dim3(256), 0, stream>>>(x, p2);
  dist_kernel<<<dim3(Nn / 128, Sn / 128), dim3(256), 0, stream>>>(x, sidx, p2, d2);
  select_kernel<<<dim3(Sn), dim3(256), 0, stream>>>(d2, cand, ccnt);
  rerank_kernel<<<dim3(Sn), dim3(64), 0, stream>>>(x, sidx, cand, ccnt, nbr);
  // conversions (xb/HT overwrite the dead d2 region)
  cvt_x_kernel<<<dim3((Bn * Nn * Cn) / (256 * 8)), dim3(256), 0, stream>>>(x, xb);
  cvt_split_kernel<<<dim3((On * Sn) / (256 * 4)), dim3(256), 0, stream>>>(W1, W1h, W1l);
  cvt_split_kernel<<<dim3((On * On) / (256 * 4)), dim3(256), 0, stream>>>(W2, W2h, W2l);
  sample_kernel<<<dim3(SAMP_ELEMS / 256), dim3(256), 0, stream>>>(x, sidx, out2);
  // MFMA GEMMs
  gemm1_mfma<<<dim3(KCn / 128, On / 128, Bn), dim3(256), 0, stream>>>(xb, W1h, W1l, b1, nbr, HT);
  gemm2_mfma<<<dim3(Cn / 4, On / 128, Bn), dim3(256), 0, stream>>>(HT, W2h, W2l, b2, feats);
}